// Round 1
// baseline (1097.199 us; speedup 1.0000x reference)
//
#include <hip/hip_runtime.h>

typedef unsigned long long u64;
typedef unsigned int u32;

#define BDIM 16
#define NP   4096
#define NC   91
#define NCM1 90
#define MSEL 4096     // top-M per image
#define KOUT 100
#define CAP  81920    // >= NP*19 = 77824 max possible candidates per image
#define SCORE_T 0.05f
#define NMS_T   0.5f
#define OFFSETF 10000.0f
#define DW_CLAMP_F 4.135166556742356f
#define WF 1333.0f
#define HF 800.0f

// ---------------- Kernel 1: softmax + threshold + candidate compaction ----------------
__global__ __launch_bounds__(256) void k_softmax(const float* __restrict__ logits,
                                                 u64* __restrict__ keys,
                                                 int* __restrict__ counts) {
    int row  = blockIdx.x * 4 + (threadIdx.x >> 6);   // one wave per row, 4 rows/block
    int lane = threadIdx.x & 63;
    const float* lg = logits + (long)row * NC;

    float v0 = lg[lane];
    float v1 = (lane < NC - 64) ? lg[64 + lane] : -3.0e38f;
    float mx = fmaxf(v0, v1);
#pragma unroll
    for (int s = 32; s; s >>= 1) mx = fmaxf(mx, __shfl_xor(mx, s));
    float e0 = expf(v0 - mx);
    float e1 = (lane < NC - 64) ? expf(v1 - mx) : 0.0f;
    float sum = e0 + e1;
#pragma unroll
    for (int s = 32; s; s >>= 1) sum += __shfl_xor(sum, s);

    float s0 = e0 / sum;
    float s1 = e1 / sum;

    int b = row >> 12;          // / NP
    int n = row & (NP - 1);

    bool p0 = (lane >= 1) && (s0 > SCORE_T);          // class = lane (skip background 0)
    bool p1 = (lane < NC - 64) && (s1 > SCORE_T);     // class = 64 + lane
    u64 m0 = __ballot(p0);
    u64 m1 = __ballot(p1);
    int cnt = __popcll(m0) + __popcll(m1);
    if (cnt) {
        int base = 0;
        if (lane == 0) base = atomicAdd(&counts[b], cnt);
        base = __shfl(base, 0);
        u64 lanemask = (1ull << lane) - 1ull;
        u64* kb = keys + (long)b * CAP;
        if (p0) {
            int pos  = base + __popcll(m0 & lanemask);
            int flat = n * NCM1 + (lane - 1);
            kb[pos] = ((u64)__float_as_uint(s0) << 32) | (u32)(~(u32)flat);
        }
        if (p1) {
            int pos  = base + __popcll(m0) + __popcll(m1 & lanemask);
            int flat = n * NCM1 + (64 + lane - 1);
            kb[pos] = ((u64)__float_as_uint(s1) << 32) | (u32)(~(u32)flat);
        }
    }
}

// ---------------- Kernel 2: per-image radix select of the M-th largest key ----------------
__global__ __launch_bounds__(1024) void k_select(const u64* __restrict__ keys,
                                                 const int* __restrict__ counts,
                                                 u64* __restrict__ thresh) {
    __shared__ int hist[2048];
    __shared__ int s_sel, s_gt;
    int b   = blockIdx.x;
    int tid = threadIdx.x;
    int n   = counts[b];
    if (n <= MSEL) { if (tid == 0) thresh[b] = 0ull; return; }

    const u64* kb = keys + (long)b * CAP;
    u64 prefix = 0, mask = 0;
    int rank = MSEL;                               // rank-th largest (1-indexed)
    const int shifts[6] = {53, 42, 31, 20, 10, 0};
    const int bitsv [6] = {11, 11, 11, 11, 10, 10};

    for (int pass = 0; pass < 6; ++pass) {
        int shift = shifts[pass];
        int nb = 1 << bitsv[pass];
        if (tid < nb) hist[tid] = 0;
        if (tid + 1024 < nb) hist[tid + 1024] = 0;
        __syncthreads();
        for (int i = tid; i < n; i += 1024) {
            u64 k = kb[i];
            if ((k & mask) == prefix)
                atomicAdd(&hist[(int)((k >> shift) & (u64)(nb - 1))], 1);
        }
        __syncthreads();
        // suffix sum: hist[j] = count of elements in bins >= j
        for (int d = 1; d < nb; d <<= 1) {
            int v0 = 0, v1 = 0;
            if (tid < nb && tid + d < nb) v0 = hist[tid + d];
            if (tid + 1024 < nb && tid + 1024 + d < nb) v1 = hist[tid + 1024 + d];
            __syncthreads();
            if (tid < nb) hist[tid] += v0;
            if (tid + 1024 < nb) hist[tid + 1024] += v1;
            __syncthreads();
        }
        // find the unique bin with cum[j] >= rank > cum[j+1]
        for (int j = tid; j < nb; j += 1024) {
            int c  = hist[j];
            int cn = (j + 1 < nb) ? hist[j + 1] : 0;
            if (c >= rank && cn < rank) { s_sel = j; s_gt = cn; }
        }
        __syncthreads();
        prefix |= ((u64)s_sel) << shift;
        mask   |= ((u64)(nb - 1)) << shift;
        rank   -= s_gt;
        __syncthreads();
    }
    if (tid == 0) thresh[b] = prefix;   // exact M-th largest key (keys distinct)
}

// ---------------- Kernel 3: compact + decode + greedy NMS per image ----------------
__global__ __launch_bounds__(1024) void k_nms(const u64* __restrict__ keys,
                                              const int* __restrict__ counts,
                                              const u64* __restrict__ thresh,
                                              const float* __restrict__ boxreg,
                                              const float* __restrict__ props,
                                              float* __restrict__ out) {
    __shared__ u64 skey[MSEL];
    __shared__ u64 wmax[16];
    __shared__ u64 s_best;
    __shared__ int s_cnt, s_pos;
    __shared__ float4 s_selbox;

    int b    = blockIdx.x;
    int tid  = threadIdx.x;
    int lane = tid & 63, wid = tid >> 6;
    int n    = counts[b];
    u64 T    = thresh[b];
    const u64* kb = keys + (long)b * CAP;

    if (tid == 0) s_cnt = 0;
    __syncthreads();
    for (int i = tid; i < n; i += 1024) {
        u64 k = kb[i];
        if (k >= T) {
            int p = atomicAdd(&s_cnt, 1);
            if (p < MSEL) skey[p] = k;
        }
    }
    __syncthreads();
    int m = s_cnt; if (m > MSEL) m = MSEL;

    // decode boxes for owned slots (i == tid + j*1024), kept in registers
    float4 rbox[4];
#pragma unroll
    for (int j = 0; j < 4; ++j) {
        int i = tid + j * 1024;
        if (i < m) {
            u64 k = skey[i];
            int flat = (int)(~(u32)k);
            int nidx = flat / NCM1;
            int c    = flat - nidx * NCM1 + 1;
            const float* pr = props + ((long)b * NP + nidx) * 4;
            float x1 = pr[0], y1 = pr[1], x2 = pr[2], y2 = pr[3];
            float w = x2 - x1, h = y2 - y1;
            float cx = x1 + 0.5f * w, cy = y1 + 0.5f * h;
            const float* rr = boxreg + (((long)b * NP + nidx) * NC + c) * 4;
            float dx = rr[0] / 10.0f, dy = rr[1] / 10.0f;
            float dw = fminf(rr[2] / 5.0f, DW_CLAMP_F);
            float dh = fminf(rr[3] / 5.0f, DW_CLAMP_F);
            // avoid FMA contraction: numpy does separate mul + add
            float pcx = __fadd_rn(__fmul_rn(dx, w), cx);
            float pcy = __fadd_rn(__fmul_rn(dy, h), cy);
            float pw = __fmul_rn(expf(dw), w);
            float ph = __fmul_rn(expf(dh), h);
            float bx1 = fminf(fmaxf(pcx - 0.5f * pw, 0.0f), WF);
            float by1 = fminf(fmaxf(pcy - 0.5f * ph, 0.0f), HF);
            float bx2 = fminf(fmaxf(pcx + 0.5f * pw, 0.0f), WF);
            float by2 = fminf(fmaxf(pcy + 0.5f * ph, 0.0f), HF);
            rbox[j] = make_float4(bx1, by1, bx2, by2);
        }
    }
    __syncthreads();

    int kdone = KOUT;
    for (int k = 0; k < KOUT; ++k) {
        // ---- argmax over remaining keys (two-level shfl reduce) ----
        u64 best = 0;
#pragma unroll
        for (int j = 0; j < 4; ++j) {
            int i = tid + j * 1024;
            if (i < m) { u64 v = skey[i]; if (v > best) best = v; }
        }
#pragma unroll
        for (int s = 32; s; s >>= 1) { u64 o = __shfl_xor(best, s); if (o > best) best = o; }
        if (lane == 0) wmax[wid] = best;
        __syncthreads();
        if (wid == 0) {
            u64 x = (lane < 16) ? wmax[lane] : 0;
#pragma unroll
            for (int s = 8; s; s >>= 1) { u64 o = __shfl_xor(x, s); if (o > x) x = o; }
            if (lane == 0) s_best = x;
        }
        __syncthreads();
        u64 ball = s_best;
        if (ball == 0ull) { kdone = k; break; }

        // ---- locate winner, broadcast its box ----
#pragma unroll
        for (int j = 0; j < 4; ++j) {
            int i = tid + j * 1024;
            if (i < m && skey[i] == ball) { s_pos = i; s_selbox = rbox[j]; }
        }
        __syncthreads();
        int pos = s_pos;
        float4 bb = s_selbox;
        int flatA   = (int)(~(u32)ball);
        int labelA  = flatA - (flatA / NCM1) * NCM1 + 1;
        float scoreA = __uint_as_float((u32)(ball >> 32));

        if (tid == 0) {
            float* ob = out + ((long)b * KOUT + k) * 4;
            ob[0] = bb.x; ob[1] = bb.y; ob[2] = bb.z; ob[3] = bb.w;
            out[BDIM * KOUT * 4 + b * KOUT + k] = scoreA;
            out[BDIM * KOUT * 5 + b * KOUT + k] = (float)labelA;
            out[BDIM * KOUT * 6 + b * KOUT + k] = 1.0f;
            skey[pos] = 0ull;    // remove winner (no other thread touches i==pos below)
        }

        // ---- suppression on class-offset coordinates (reference expression order) ----
        float offA = (float)labelA * OFFSETF;
        float ax1 = bb.x + offA, ay1 = bb.y + offA, ax2 = bb.z + offA, ay2 = bb.w + offA;
        float areaA = (ax2 - ax1) * (ay2 - ay1);
#pragma unroll
        for (int j = 0; j < 4; ++j) {
            int i = tid + j * 1024;
            if (i < m && i != pos) {
                u64 v = skey[i];
                if (v) {
                    int flatB  = (int)(~(u32)v);
                    int labelB = flatB - (flatB / NCM1) * NCM1 + 1;
                    float offB = (float)labelB * OFFSETF;
                    float4 cb = rbox[j];
                    float bx1 = cb.x + offB, by1 = cb.y + offB;
                    float bx2 = cb.z + offB, by2 = cb.w + offB;
                    float areaB = (bx2 - bx1) * (by2 - by1);
                    float iw = fmaxf(fminf(ax2, bx2) - fmaxf(ax1, bx1), 0.0f);
                    float ih = fmaxf(fminf(ay2, by2) - fmaxf(ay1, by1), 0.0f);
                    float inter = iw * ih;
                    float denom = areaB + areaA - inter + 1e-9f;
                    float iou = inter / denom;
                    if (iou > NMS_T) skey[i] = 0ull;
                }
            }
        }
        __syncthreads();
    }

    // fill remaining slots as invalid
    for (int k = kdone + tid; k < KOUT; k += 1024) {
        float* ob = out + ((long)b * KOUT + k) * 4;
        ob[0] = 0.0f; ob[1] = 0.0f; ob[2] = 0.0f; ob[3] = 0.0f;
        out[BDIM * KOUT * 4 + b * KOUT + k] = 0.0f;
        out[BDIM * KOUT * 5 + b * KOUT + k] = -1.0f;
        out[BDIM * KOUT * 6 + b * KOUT + k] = 0.0f;
    }
}

extern "C" void kernel_launch(void* const* d_in, const int* in_sizes, int n_in,
                              void* d_out, int out_size, void* d_ws, size_t ws_size,
                              hipStream_t stream) {
    const float* logits = (const float*)d_in[0];
    const float* boxreg = (const float*)d_in[1];
    const float* props  = (const float*)d_in[2];
    float* out = (float*)d_out;

    char* ws = (char*)d_ws;
    int* counts = (int*)ws;                 // 64 B
    u64* thresh = (u64*)(ws + 256);         // 128 B
    u64* keys   = (u64*)(ws + 1024);        // 16 * 81920 * 8 = 10.5 MB

    hipMemsetAsync(counts, 0, BDIM * sizeof(int), stream);
    k_softmax<<<(BDIM * NP) / 4, 256, 0, stream>>>(logits, keys, counts);
    k_select<<<BDIM, 1024, 0, stream>>>(keys, counts, thresh);
    k_nms<<<BDIM, 1024, 0, stream>>>(keys, counts, thresh, boxreg, props, out);
}

// Round 2
// 525.832 us; speedup vs baseline: 2.0866x; 2.0866x over previous
//
#include <hip/hip_runtime.h>

typedef unsigned long long u64;
typedef unsigned int u32;

#define BDIM 16
#define NP   4096
#define NC   91
#define NCM1 90
#define MSEL 4096     // top-M per image
#define KOUT 100
#define RSLOT 19      // max candidates per row: scores sum to 1, >0.05 => <=19
#define CAP  (NP * RSLOT)   // 77824 fixed slots per image
#define SCORE_T 0.05f
#define NMS_T   0.5f
#define OFFSETF 10000.0f
#define DW_CLAMP_F 4.135166556742356f
#define WF 1333.0f
#define HF 800.0f

#define TNMS 256
#define SLOTS (MSEL / TNMS)   // 16 register-resident candidates per thread

// ---------------- Kernel 1: softmax + threshold -> fixed-slot keys (atomic-free) ----------------
__global__ __launch_bounds__(256) void k_softmax(const float* __restrict__ logits,
                                                 u64* __restrict__ keys) {
    int row  = blockIdx.x * 4 + (threadIdx.x >> 6);   // one wave per row
    int lane = threadIdx.x & 63;
    const float* lg = logits + (long)row * NC;

    float v0 = lg[lane];
    float v1 = (lane < NC - 64) ? lg[64 + lane] : -3.0e38f;
    float mx = fmaxf(v0, v1);
#pragma unroll
    for (int s = 32; s; s >>= 1) mx = fmaxf(mx, __shfl_xor(mx, s));
    float e0 = expf(v0 - mx);
    float e1 = (lane < NC - 64) ? expf(v1 - mx) : 0.0f;
    float sum = e0 + e1;
#pragma unroll
    for (int s = 32; s; s >>= 1) sum += __shfl_xor(sum, s);

    float s0 = e0 / sum;
    float s1 = e1 / sum;

    int b = row >> 12;          // / NP
    int n = row & (NP - 1);

    bool p0 = (lane >= 1) && (s0 > SCORE_T);          // class = lane (skip background 0)
    bool p1 = (lane < NC - 64) && (s1 > SCORE_T);     // class = 64 + lane
    u64 m0 = __ballot(p0);
    u64 m1 = __ballot(p1);
    int c0  = __popcll(m0);
    int cnt = c0 + __popcll(m1);

    u64 lanemask = (1ull << lane) - 1ull;
    u64* kb = keys + (long)b * CAP + (long)n * RSLOT;
    if (p0) {
        int pos  = __popcll(m0 & lanemask);
        int flat = n * NCM1 + (lane - 1);
        kb[pos] = ((u64)__float_as_uint(s0) << 32) | (u32)(~(u32)flat);
    }
    if (p1) {
        int pos  = c0 + __popcll(m1 & lanemask);
        int flat = n * NCM1 + (64 + lane - 1);
        kb[pos] = ((u64)__float_as_uint(s1) << 32) | (u32)(~(u32)flat);
    }
    // zero-fill unused slots (disjoint from key slots -> no ordering hazard)
    if (lane < RSLOT - cnt) kb[cnt + lane] = 0ull;
}

// ---------------- Kernel 2: per-image radix select of the M-th largest key ----------------
// Zero-padded array: if fewer than MSEL valid (nonzero) keys, result is 0 -> take-all.
__global__ __launch_bounds__(1024) void k_select(const u64* __restrict__ keys,
                                                 u64* __restrict__ thresh) {
    __shared__ int hist[2048];
    __shared__ int s_sel, s_gt;
    int b   = blockIdx.x;
    int tid = threadIdx.x;

    const u64* kb = keys + (long)b * CAP;
    u64 prefix = 0, mask = 0;
    int rank = MSEL;                               // rank-th largest (1-indexed)
    const int shifts[6] = {53, 42, 31, 20, 10, 0};
    const int bitsv [6] = {11, 11, 11, 11, 10, 10};

    for (int pass = 0; pass < 6; ++pass) {
        int shift = shifts[pass];
        int nb = 1 << bitsv[pass];
        if (tid < nb) hist[tid] = 0;
        if (tid + 1024 < nb) hist[tid + 1024] = 0;
        __syncthreads();
        for (int i = tid; i < CAP; i += 1024) {
            u64 k = kb[i];
            if ((k & mask) == prefix)
                atomicAdd(&hist[(int)((k >> shift) & (u64)(nb - 1))], 1);
        }
        __syncthreads();
        // suffix sum: hist[j] = count of elements in bins >= j
        for (int d = 1; d < nb; d <<= 1) {
            int v0 = 0, v1 = 0;
            if (tid < nb && tid + d < nb) v0 = hist[tid + d];
            if (tid + 1024 < nb && tid + 1024 + d < nb) v1 = hist[tid + 1024 + d];
            __syncthreads();
            if (tid < nb) hist[tid] += v0;
            if (tid + 1024 < nb) hist[tid + 1024] += v1;
            __syncthreads();
        }
        // find the unique bin with cum[j] >= rank > cum[j+1]
        for (int j = tid; j < nb; j += 1024) {
            int c  = hist[j];
            int cn = (j + 1 < nb) ? hist[j + 1] : 0;
            if (c >= rank && cn < rank) { s_sel = j; s_gt = cn; }
        }
        __syncthreads();
        prefix |= ((u64)s_sel) << shift;
        mask   |= ((u64)(nb - 1)) << shift;
        rank   -= s_gt;
        __syncthreads();
    }
    if (tid == 0) thresh[b] = prefix;
}

// ---------------- Kernel 3: compact + decode + greedy NMS (register-resident) ----------------
__global__ __launch_bounds__(TNMS) void k_nms(const u64* __restrict__ keys,
                                              const u64* __restrict__ thresh,
                                              const float* __restrict__ boxreg,
                                              const float* __restrict__ props,
                                              float* __restrict__ out) {
    __shared__ u64 skey[MSEL];
    __shared__ u64 wred[TNMS / 64];
    __shared__ u64 s_best;
    __shared__ int s_cnt;
    __shared__ float4 s_box;

    int b    = blockIdx.x;
    int tid  = threadIdx.x;
    int lane = tid & 63, wid = tid >> 6;
    u64 T    = thresh[b];
    const u64* kb = keys + (long)b * CAP;

    if (tid == 0) s_cnt = 0;
    __syncthreads();
    for (int i = tid; i < CAP; i += TNMS) {
        u64 k = kb[i];
        if (k && k >= T) {
            int p = atomicAdd(&s_cnt, 1);
            if (p < MSEL) skey[p] = k;
        }
    }
    __syncthreads();
    int m = s_cnt; if (m > MSEL) m = MSEL;

    // pull owned candidates into registers; decode boxes
    u64 rkey[SLOTS];
    float4 rbox[SLOTS];
#pragma unroll
    for (int j = 0; j < SLOTS; ++j) {
        int i = tid + j * TNMS;
        rkey[j] = (i < m) ? skey[i] : 0ull;
        if (rkey[j]) {
            u64 k = rkey[j];
            int flat = (int)(~(u32)k);
            int nidx = flat / NCM1;
            int c    = flat - nidx * NCM1 + 1;
            const float* pr = props + ((long)b * NP + nidx) * 4;
            float x1 = pr[0], y1 = pr[1], x2 = pr[2], y2 = pr[3];
            float w = x2 - x1, h = y2 - y1;
            float cx = x1 + 0.5f * w, cy = y1 + 0.5f * h;
            const float* rr = boxreg + (((long)b * NP + nidx) * NC + c) * 4;
            float dx = rr[0] / 10.0f, dy = rr[1] / 10.0f;
            float dw = fminf(rr[2] / 5.0f, DW_CLAMP_F);
            float dh = fminf(rr[3] / 5.0f, DW_CLAMP_F);
            // avoid FMA contraction: numpy does separate mul + add
            float pcx = __fadd_rn(__fmul_rn(dx, w), cx);
            float pcy = __fadd_rn(__fmul_rn(dy, h), cy);
            float pw = __fmul_rn(expf(dw), w);
            float ph = __fmul_rn(expf(dh), h);
            float bx1 = fminf(fmaxf(pcx - 0.5f * pw, 0.0f), WF);
            float by1 = fminf(fmaxf(pcy - 0.5f * ph, 0.0f), HF);
            float bx2 = fminf(fmaxf(pcx + 0.5f * pw, 0.0f), WF);
            float by2 = fminf(fmaxf(pcy + 0.5f * ph, 0.0f), HF);
            rbox[j] = make_float4(bx1, by1, bx2, by2);
        }
    }

    int kdone = KOUT;
    for (int k = 0; k < KOUT; ++k) {
        // ---- argmax over remaining keys (registers -> wave shfl -> cross-wave LDS) ----
        u64 best = 0;
#pragma unroll
        for (int j = 0; j < SLOTS; ++j) if (rkey[j] > best) best = rkey[j];
#pragma unroll
        for (int s = 32; s; s >>= 1) { u64 o = __shfl_xor(best, s); if (o > best) best = o; }
        if (lane == 0) wred[wid] = best;
        __syncthreads();
        if (wid == 0) {
            u64 x = (lane < TNMS / 64) ? wred[lane] : 0;
#pragma unroll
            for (int s = TNMS / 128; s; s >>= 1) { u64 o = __shfl_xor(x, s); if (o > x) x = o; }
            if (lane == 0) s_best = x;
        }
        __syncthreads();
        u64 ball = s_best;
        if (ball == 0ull) { kdone = k; break; }

        int flatA   = (int)(~(u32)ball);
        int labelA  = flatA - (flatA / NCM1) * NCM1 + 1;
        float scoreA = __uint_as_float((u32)(ball >> 32));

        // ---- winner thread: publish box, emit output, retire its key ----
#pragma unroll
        for (int j = 0; j < SLOTS; ++j) {
            if (rkey[j] == ball) {
                s_box = rbox[j];
                rkey[j] = 0ull;
                float* ob = out + ((long)b * KOUT + k) * 4;
                ob[0] = rbox[j].x; ob[1] = rbox[j].y; ob[2] = rbox[j].z; ob[3] = rbox[j].w;
                out[BDIM * KOUT * 4 + b * KOUT + k] = scoreA;
                out[BDIM * KOUT * 5 + b * KOUT + k] = (float)labelA;
                out[BDIM * KOUT * 6 + b * KOUT + k] = 1.0f;
            }
        }
        __syncthreads();
        float4 bb = s_box;

        // ---- suppression on class-offset coordinates (reference expression order) ----
        float offA = (float)labelA * OFFSETF;
        float ax1 = bb.x + offA, ay1 = bb.y + offA, ax2 = bb.z + offA, ay2 = bb.w + offA;
        float areaA = (ax2 - ax1) * (ay2 - ay1);
#pragma unroll
        for (int j = 0; j < SLOTS; ++j) {
            u64 v = rkey[j];
            if (v) {
                int flatB  = (int)(~(u32)v);
                int labelB = flatB - (flatB / NCM1) * NCM1 + 1;
                float offB = (float)labelB * OFFSETF;
                float4 cb = rbox[j];
                float bx1 = cb.x + offB, by1 = cb.y + offB;
                float bx2 = cb.z + offB, by2 = cb.w + offB;
                float areaB = (bx2 - bx1) * (by2 - by1);
                float iw = fmaxf(fminf(ax2, bx2) - fmaxf(ax1, bx1), 0.0f);
                float ih = fmaxf(fminf(ay2, by2) - fmaxf(ay1, by1), 0.0f);
                float inter = iw * ih;
                float denom = areaB + areaA - inter + 1e-9f;
                float iou = inter / denom;
                if (iou > NMS_T) rkey[j] = 0ull;
            }
        }
        // no barrier needed here: next argmax reads only registers, and wred/s_box
        // rewrites are separated from their readers by the two barriers above.
    }

    // fill remaining slots as invalid
    for (int k = kdone + tid; k < KOUT; k += TNMS) {
        float* ob = out + ((long)b * KOUT + k) * 4;
        ob[0] = 0.0f; ob[1] = 0.0f; ob[2] = 0.0f; ob[3] = 0.0f;
        out[BDIM * KOUT * 4 + b * KOUT + k] = 0.0f;
        out[BDIM * KOUT * 5 + b * KOUT + k] = -1.0f;
        out[BDIM * KOUT * 6 + b * KOUT + k] = 0.0f;
    }
}

extern "C" void kernel_launch(void* const* d_in, const int* in_sizes, int n_in,
                              void* d_out, int out_size, void* d_ws, size_t ws_size,
                              hipStream_t stream) {
    const float* logits = (const float*)d_in[0];
    const float* boxreg = (const float*)d_in[1];
    const float* props  = (const float*)d_in[2];
    float* out = (float*)d_out;

    char* ws = (char*)d_ws;
    u64* thresh = (u64*)ws;                 // 128 B
    u64* keys   = (u64*)(ws + 1024);        // 16 * 77824 * 8 = 9.96 MB

    k_softmax<<<(BDIM * NP) / 4, 256, 0, stream>>>(logits, keys);
    k_select<<<BDIM, 1024, 0, stream>>>(keys, thresh);
    k_nms<<<BDIM, TNMS, 0, stream>>>(keys, thresh, boxreg, props, out);
}

// Round 3
// 329.881 us; speedup vs baseline: 3.3260x; 1.5940x over previous
//
#include <hip/hip_runtime.h>

typedef unsigned long long u64;
typedef unsigned int u32;

#define BDIM 16
#define NP   4096
#define NC   91
#define NCM1 90
#define MSEL 4096     // top-M per image
#define KOUT 100
#define RSLOT 19      // max candidates per row: scores sum to 1, >0.05 => <=19
#define CAP  (NP * RSLOT)   // 77824 fixed slots per image
#define SCORE_T 0.05f
#define NMS_T   0.5f
#define OFFSETF 10000.0f
#define DW_CLAMP_F 4.135166556742356f
#define WF 1333.0f
#define HF 800.0f

#define TN 1024
#define SL (MSEL / TN)    // 4 register-resident candidates per thread

// ---------------- Kernel 1: softmax + threshold -> fixed-slot keys (atomic-free) ----------------
__global__ __launch_bounds__(256) void k_softmax(const float* __restrict__ logits,
                                                 u64* __restrict__ keys) {
    int row  = blockIdx.x * 4 + (threadIdx.x >> 6);   // one wave per row
    int lane = threadIdx.x & 63;
    const float* lg = logits + (long)row * NC;

    float v0 = lg[lane];
    float v1 = (lane < NC - 64) ? lg[64 + lane] : -3.0e38f;
    float mx = fmaxf(v0, v1);
#pragma unroll
    for (int s = 32; s; s >>= 1) mx = fmaxf(mx, __shfl_xor(mx, s));
    float e0 = expf(v0 - mx);
    float e1 = (lane < NC - 64) ? expf(v1 - mx) : 0.0f;
    float sum = e0 + e1;
#pragma unroll
    for (int s = 32; s; s >>= 1) sum += __shfl_xor(sum, s);

    float s0 = e0 / sum;
    float s1 = e1 / sum;

    int b = row >> 12;          // / NP
    int n = row & (NP - 1);

    bool p0 = (lane >= 1) && (s0 > SCORE_T);          // class = lane (skip background 0)
    bool p1 = (lane < NC - 64) && (s1 > SCORE_T);     // class = 64 + lane
    u64 m0 = __ballot(p0);
    u64 m1 = __ballot(p1);
    int c0  = __popcll(m0);
    int cnt = c0 + __popcll(m1);

    u64 lanemask = (1ull << lane) - 1ull;
    u64* kb = keys + (long)b * CAP + (long)n * RSLOT;
    if (p0) {
        int pos  = __popcll(m0 & lanemask);
        int flat = n * NCM1 + (lane - 1);
        kb[pos] = ((u64)__float_as_uint(s0) << 32) | (u32)(~(u32)flat);
    }
    if (p1) {
        int pos  = c0 + __popcll(m1 & lanemask);
        int flat = n * NCM1 + (64 + lane - 1);
        kb[pos] = ((u64)__float_as_uint(s1) << 32) | (u32)(~(u32)flat);
    }
    // zero-fill unused slots (disjoint from key slots -> no ordering hazard)
    if (lane < RSLOT - cnt) kb[cnt + lane] = 0ull;
}

// ---------------- Kernel 2: per-image radix select of the M-th largest key ----------------
// Zero-padded array: if fewer than MSEL valid (nonzero) keys, result is 0 -> take-all.
__global__ __launch_bounds__(1024) void k_select(const u64* __restrict__ keys,
                                                 u64* __restrict__ thresh) {
    __shared__ int hist[2048];
    __shared__ int s_sel, s_gt;
    int b   = blockIdx.x;
    int tid = threadIdx.x;

    const u64* kb = keys + (long)b * CAP;
    u64 prefix = 0, mask = 0;
    int rank = MSEL;                               // rank-th largest (1-indexed)
    const int shifts[6] = {53, 42, 31, 20, 10, 0};
    const int bitsv [6] = {11, 11, 11, 11, 10, 10};

    for (int pass = 0; pass < 6; ++pass) {
        int shift = shifts[pass];
        int nb = 1 << bitsv[pass];
        if (tid < nb) hist[tid] = 0;
        if (tid + 1024 < nb) hist[tid + 1024] = 0;
        __syncthreads();
        for (int i = tid; i < CAP; i += 1024) {
            u64 k = kb[i];
            if ((k & mask) == prefix)
                atomicAdd(&hist[(int)((k >> shift) & (u64)(nb - 1))], 1);
        }
        __syncthreads();
        // suffix sum: hist[j] = count of elements in bins >= j
        for (int d = 1; d < nb; d <<= 1) {
            int v0 = 0, v1 = 0;
            if (tid < nb && tid + d < nb) v0 = hist[tid + d];
            if (tid + 1024 < nb && tid + 1024 + d < nb) v1 = hist[tid + 1024 + d];
            __syncthreads();
            if (tid < nb) hist[tid] += v0;
            if (tid + 1024 < nb) hist[tid + 1024] += v1;
            __syncthreads();
        }
        // find the unique bin with cum[j] >= rank > cum[j+1]
        for (int j = tid; j < nb; j += 1024) {
            int c  = hist[j];
            int cn = (j + 1 < nb) ? hist[j + 1] : 0;
            if (c >= rank && cn < rank) { s_sel = j; s_gt = cn; }
        }
        __syncthreads();
        prefix |= ((u64)s_sel) << shift;
        mask   |= ((u64)(nb - 1)) << shift;
        rank   -= s_gt;
        __syncthreads();
    }
    if (tid == 0) thresh[b] = prefix;
}

// ---------------- Kernel 3: compact + decode + greedy NMS (register-resident, no spill) ----------------
__global__ __launch_bounds__(TN) void k_nms(const u64* __restrict__ keys,
                                            const u64* __restrict__ thresh,
                                            const float* __restrict__ boxreg,
                                            const float* __restrict__ props,
                                            float* __restrict__ out) {
    __shared__ u64 skey[MSEL];          // 32 KB staging for compacted keys
    __shared__ u64 wred[TN / 64];
    __shared__ u64 s_best;
    __shared__ int s_cnt;
    __shared__ float4 s_obox;
    __shared__ float s_area;
    __shared__ int s_lab;

    int b    = blockIdx.x;
    int tid  = threadIdx.x;
    int lane = tid & 63, wid = tid >> 6;
    u64 T    = thresh[b];
    const u64* kb = keys + (long)b * CAP;

    if (tid == 0) s_cnt = 0;
    for (int i = tid; i < MSEL; i += TN) skey[i] = 0ull;
    __syncthreads();

    // wave-aggregated compaction: one LDS atomic per wave per iteration
    u64 lanemask = (1ull << lane) - 1ull;
    for (int i = tid; i < CAP; i += TN) {          // CAP % TN == 0: no divergence
        u64 k = kb[i];
        bool pred = (k != 0ull) && (k >= T);
        u64 mb = __ballot(pred);
        int cnt = __popcll(mb);
        int base = 0;
        if (lane == 0 && cnt) base = atomicAdd(&s_cnt, cnt);
        base = __shfl(base, 0);
        if (pred) {
            int pos = base + __popcll(mb & lanemask);
            if (pos < MSEL) skey[pos] = k;
        }
    }
    __syncthreads();
    int m = s_cnt; if (m > MSEL) m = MSEL;

    // pull owned candidates into registers; decode once (raw box, offset box, area, label)
    u64 rkey[SL];
    float4 rraw[SL];     // clipped box (output)
    float4 robx[SL];     // offset box (NMS coords)
    float rarea[SL];
    int rlab[SL];
#pragma unroll
    for (int j = 0; j < SL; ++j) {
        int i = tid + j * TN;
        rkey[j] = (i < m) ? skey[i] : 0ull;
        if (rkey[j]) {
            u64 k = rkey[j];
            int flat = (int)(~(u32)k);
            int nidx = flat / NCM1;
            int c    = flat - nidx * NCM1 + 1;
            const float* pr = props + ((long)b * NP + nidx) * 4;
            float x1 = pr[0], y1 = pr[1], x2 = pr[2], y2 = pr[3];
            float w = x2 - x1, h = y2 - y1;
            float cx = x1 + 0.5f * w, cy = y1 + 0.5f * h;
            const float* rr = boxreg + (((long)b * NP + nidx) * NC + c) * 4;
            float dx = rr[0] / 10.0f, dy = rr[1] / 10.0f;
            float dw = fminf(rr[2] / 5.0f, DW_CLAMP_F);
            float dh = fminf(rr[3] / 5.0f, DW_CLAMP_F);
            // avoid FMA contraction: numpy does separate mul + add
            float pcx = __fadd_rn(__fmul_rn(dx, w), cx);
            float pcy = __fadd_rn(__fmul_rn(dy, h), cy);
            float pw = __fmul_rn(expf(dw), w);
            float ph = __fmul_rn(expf(dh), h);
            float bx1 = fminf(fmaxf(pcx - 0.5f * pw, 0.0f), WF);
            float by1 = fminf(fmaxf(pcy - 0.5f * ph, 0.0f), HF);
            float bx2 = fminf(fmaxf(pcx + 0.5f * pw, 0.0f), WF);
            float by2 = fminf(fmaxf(pcy + 0.5f * ph, 0.0f), HF);
            rraw[j] = make_float4(bx1, by1, bx2, by2);
            float offB = (float)c * OFFSETF;
            float ox1 = bx1 + offB, oy1 = by1 + offB;
            float ox2 = bx2 + offB, oy2 = by2 + offB;
            robx[j] = make_float4(ox1, oy1, ox2, oy2);
            rarea[j] = (ox2 - ox1) * (oy2 - oy1);
            rlab[j] = c;
        }
    }

    int kdone = KOUT;
    for (int k = 0; k < KOUT; ++k) {
        // ---- argmax over remaining keys (registers -> wave shfl -> cross-wave LDS) ----
        u64 best = 0;
#pragma unroll
        for (int j = 0; j < SL; ++j) if (rkey[j] > best) best = rkey[j];
#pragma unroll
        for (int s = 32; s; s >>= 1) { u64 o = __shfl_xor(best, s); if (o > best) best = o; }
        if (lane == 0) wred[wid] = best;
        __syncthreads();
        if (wid == 0) {
            u64 x = (lane < TN / 64) ? wred[lane] : 0;
#pragma unroll
            for (int s = TN / 128; s; s >>= 1) { u64 o = __shfl_xor(x, s); if (o > x) x = o; }
            if (lane == 0) s_best = x;
        }
        __syncthreads();
        u64 ball = s_best;
        if (ball == 0ull) { kdone = k; break; }

        float scoreA = __uint_as_float((u32)(ball >> 32));

        // ---- winner thread: publish offset box/area/label, emit output, retire key ----
#pragma unroll
        for (int j = 0; j < SL; ++j) {
            if (rkey[j] == ball) {
                s_obox = robx[j];
                s_area = rarea[j];
                s_lab  = rlab[j];
                rkey[j] = 0ull;
                float* ob = out + ((long)b * KOUT + k) * 4;
                ob[0] = rraw[j].x; ob[1] = rraw[j].y; ob[2] = rraw[j].z; ob[3] = rraw[j].w;
                out[BDIM * KOUT * 4 + b * KOUT + k] = scoreA;
                out[BDIM * KOUT * 5 + b * KOUT + k] = (float)rlab[j];
                out[BDIM * KOUT * 6 + b * KOUT + k] = 1.0f;
            }
        }
        __syncthreads();
        float4 A = s_obox;
        float areaA = s_area;
        int labA = s_lab;

        // ---- suppression: cross-class IoU is always 0 -> label early-out ----
#pragma unroll
        for (int j = 0; j < SL; ++j) {
            if (rkey[j] && rlab[j] == labA) {
                float4 Bv = robx[j];
                float iw = fmaxf(fminf(A.z, Bv.z) - fmaxf(A.x, Bv.x), 0.0f);
                float ih = fmaxf(fminf(A.w, Bv.w) - fmaxf(A.y, Bv.y), 0.0f);
                float inter = iw * ih;
                float denom = rarea[j] + areaA - inter + 1e-9f;
                float iou = inter / denom;
                if (iou > NMS_T) rkey[j] = 0ull;
            }
        }
        // no barrier needed: suppression is register-only; wred/s_obox rewrites are
        // separated from their readers by the two barriers at the top of the loop.
    }

    // fill remaining slots as invalid
    for (int k = kdone + tid; k < KOUT; k += TN) {
        float* ob = out + ((long)b * KOUT + k) * 4;
        ob[0] = 0.0f; ob[1] = 0.0f; ob[2] = 0.0f; ob[3] = 0.0f;
        out[BDIM * KOUT * 4 + b * KOUT + k] = 0.0f;
        out[BDIM * KOUT * 5 + b * KOUT + k] = -1.0f;
        out[BDIM * KOUT * 6 + b * KOUT + k] = 0.0f;
    }
}

extern "C" void kernel_launch(void* const* d_in, const int* in_sizes, int n_in,
                              void* d_out, int out_size, void* d_ws, size_t ws_size,
                              hipStream_t stream) {
    const float* logits = (const float*)d_in[0];
    const float* boxreg = (const float*)d_in[1];
    const float* props  = (const float*)d_in[2];
    float* out = (float*)d_out;

    char* ws = (char*)d_ws;
    u64* thresh = (u64*)ws;                 // 128 B
    u64* keys   = (u64*)(ws + 1024);        // 16 * 77824 * 8 = 9.96 MB

    k_softmax<<<(BDIM * NP) / 4, 256, 0, stream>>>(logits, keys);
    k_select<<<BDIM, 1024, 0, stream>>>(keys, thresh);
    k_nms<<<BDIM, TN, 0, stream>>>(keys, thresh, boxreg, props, out);
}